// Round 12
// baseline (101.570 us; speedup 1.0000x reference)
//
#include <hip/hip_runtime.h>
#include <math.h>

typedef __bf16 bf16;
typedef __bf16 bf16x4 __attribute__((ext_vector_type(4)));
typedef __bf16 bf16x8 __attribute__((ext_vector_type(8)));
typedef float f32x4 __attribute__((ext_vector_type(4)));

#define MFMA16(a,b,c) __builtin_amdgcn_mfma_f32_16x16x32_bf16((a),(b),(c),0,0,0)

static constexpr int HS  = 64;    // head size
static constexpr int SEQ = 2048;  // sequence length
static constexpr int NE  = 1024;  // n_embed
static constexpr int NB  = 8;     // batch

__device__ __forceinline__ bf16x8 cvt8(float4 a, float4 b) {
  bf16x8 r;
  r[0]=(bf16)a.x; r[1]=(bf16)a.y; r[2]=(bf16)a.z; r[3]=(bf16)a.w;
  r[4]=(bf16)b.x; r[5]=(bf16)b.y; r[6]=(bf16)b.z; r[7]=(bf16)b.w;
  return r;
}

// async global->LDS, 16 bytes per lane (lds dest = wave-uniform base + lane*16)
__device__ __forceinline__ void gload16(const void* g, void* l) {
  __builtin_amdgcn_global_load_lds(
      (const __attribute__((address_space(1))) void*)g,
      (__attribute__((address_space(3))) void*)l, 16, 0, 0);
}

// ---- W f32 -> bf16 (Wq pre-scaled by 1/sqrt(64)) ----
__global__ __launch_bounds__(256) void wcvt_kernel(
    const float* __restrict__ Wq, const float* __restrict__ Wk,
    const float* __restrict__ Wv, bf16* __restrict__ wqb,
    bf16* __restrict__ wkb, bf16* __restrict__ wvb)
{
  int i = (blockIdx.x * 256 + threadIdx.x) * 4;   // 64 blocks -> 65536 elems
  float4 q = *(const float4*)(Wq + i);
  float4 k = *(const float4*)(Wk + i);
  float4 v = *(const float4*)(Wv + i);
  bf16x4 qo, ko, vo;
  qo[0]=(bf16)(q.x*0.125f); qo[1]=(bf16)(q.y*0.125f); qo[2]=(bf16)(q.z*0.125f); qo[3]=(bf16)(q.w*0.125f);
  ko[0]=(bf16)k.x; ko[1]=(bf16)k.y; ko[2]=(bf16)k.z; ko[3]=(bf16)k.w;
  vo[0]=(bf16)v.x; vo[1]=(bf16)v.y; vo[2]=(bf16)v.z; vo[3]=(bf16)v.w;
  *(bf16x4*)(wqb + i) = qo;
  *(bf16x4*)(wkb + i) = ko;
  *(bf16x4*)(wvb + i) = vo;
}

// ---- projection: X via global_load_lds (32KB LDS), W direct global->reg ----
// grid 768 x 256thr: blocks [0,256)=q, [256,512)=k, [512,768)=v — uniform.
// W (128KB/matrix) is L2-resident and identical across the block's 4 waves:
// read B-frags directly inside compute (L1 broadcast), no W LDS staging.
// LDS = 32KB (X dbuf only) -> 5 blocks/CU (20 waves) to hide the per-step
// barrier drain that has been the limiter since R5.
template<int TRANS>
__device__ __forceinline__ void proj_body(
    const float* __restrict__ X, const bf16* __restrict__ W,
    bf16* __restrict__ outN, bf16* __restrict__ outT, int slab, char* Xb)
{
  const int tid  = threadIdx.x;
  const int lane = tid & 63;
  const int w    = tid >> 6;
  const int m    = lane & 15;
  const int g    = lane >> 4;
  const int rowBase = slab * 64;

  const f32x4 vz = {0.f,0.f,0.f,0.f};
  f32x4 acc[4] = {vz, vz, vz, vz};

  const float* Xbase = X + (size_t)rowBase * NE;
  const bf16*  Wrow  = W + (size_t)m * NE + g * 8;  // + 16n*NE + kt*64 + kk*32

  auto stage = [&](int kt, int buf) {
    // X: 4 instrs/thread; instr q covers rows (q*4+w)*4 .. +3 (1024B each)
#pragma unroll
    for (int q = 0; q < 4; ++q) {
      int r = (q*4 + w)*4 + (lane >> 4);
      int s = lane & 15;
      const float* src = Xbase + (size_t)r * NE + kt*64 + ((s ^ (r & 15)) * 4);
      gload16(src, Xb + buf*16384 + (q*4 + w)*1024);   // wave-uniform base
    }
  };

  auto compute = [&](int buf, int kt) {
#pragma unroll
    for (int kk = 0; kk < 2; ++kk) {
      const int arow = 16*w + m;
      const int s0 = 2*(kk*4 + g);
      const char* ab = Xb + buf*16384 + arow*256;
      float4 x0 = *(const float4*)(ab + (( s0      ^ (arow & 15)) * 16));
      float4 x1 = *(const float4*)(ab + (((s0 + 1) ^ (arow & 15)) * 16));
      bf16x8 af = cvt8(x0, x1);
#pragma unroll
      for (int n = 0; n < 4; ++n) {
        // B slot j = W[16n+m][kt*64 + kk*32 + g*8 + j] — same k-bijection as A
        bf16x8 b = *(const bf16x8*)(Wrow + (size_t)(16*n) * NE + kt*64 + kk*32);
        acc[n] = MFMA16(af, b, acc[n]);
      }
    }
  };

  stage(0, 0);
  __syncthreads();            // drains stage-0
  int buf = 0;
  for (int kt = 0; kt < 16; ++kt) {
    if (kt + 1 < 16) stage(kt + 1, buf ^ 1);   // async prefetch
    compute(buf, kt);
    __syncthreads();          // drains prefetch + guards LDS reuse
    buf ^= 1;
  }

  // C/D: col = lane&15, row = 4*(lane>>4)+i  [m89-verified]
#pragma unroll
  for (int n = 0; n < 4; ++n)
#pragma unroll
    for (int i = 0; i < 4; ++i) {
      int row = rowBase + 16*w + 4*g + i;
      int h   = 16*n + m;
      if (!TRANS)
        outN[(size_t)row * HS + h] = (bf16)acc[n][i];
      else
        outT[((size_t)(row >> 11) * HS + h) * SEQ + (row & 2047)] =
            (bf16)acc[n][i];
    }
}

__global__ __launch_bounds__(256, 4) void proj_kernel(
    const float* __restrict__ index, const float* __restrict__ memory,
    const bf16* __restrict__ wqb, const bf16* __restrict__ wkb,
    const bf16* __restrict__ wvb, bf16* __restrict__ qb,
    bf16* __restrict__ kb, bf16* __restrict__ vtb)
{
  __shared__ __align__(1024) char Xb[32768];   // f32 X tile, 2 buffers (32KB)
  const int bid = blockIdx.x;
  if (bid < 256)
    proj_body<0>(index,  wqb, qb, nullptr, bid,       Xb);
  else if (bid < 512)
    proj_body<0>(memory, wkb, kb, nullptr, bid - 256, Xb);
  else
    proj_body<1>(memory, wvb, nullptr, vtb, bid - 512, Xb);
}

// ---- flash attention: swapped-operand softmax (T12), unchanged from R11 ----
__global__ __launch_bounds__(128) void attn_kernel(
    const bf16* __restrict__ qb, const bf16* __restrict__ kb,
    const bf16* __restrict__ vtb, float* __restrict__ out)
{
  __shared__ __align__(16) bf16 Ks[2][64][72];    // per-wave K tile [kv][d]
  __shared__ __align__(16) bf16 VTs[2][64][72];   // per-wave V^T tile [d][kv]
  __shared__ __align__(16) bf16 Ps[2][16][72];    // per-wave P [q][kv]

  const int tid  = threadIdx.x;
  const int lane = tid & 63;
  const int w    = tid >> 6;
  const int m    = lane & 15;
  const int g    = lane >> 4;
  const int qt   = 127 - blockIdx.x;   // reversed: longest blocks first
  const int b    = blockIdx.y;
  const int nkv  = (qt >> 2) + 1;
  const int r0   = lane >> 1;
  const int hh   = (lane & 1) * 32;

  bf16x8 qf0 = *(const bf16x8*)(qb + ((size_t)b*SEQ + qt*16 + m)*HS + g*8);
  bf16x8 qf1 = *(const bf16x8*)(qb + ((size_t)b*SEQ + qt*16 + m)*HS + 32 + g*8);

  const f32x4 vz = {0.f,0.f,0.f,0.f};
  f32x4 o_acc[4] = {vz, vz, vz, vz};   // O^T[d=16nd+4g+i][q=m]
  float mrun = -INFINITY, lrun = 0.f;  // row-uniform state for q-row m

  bf16x8 kp[8], vp[8];
  const bf16* kbB = kb  + (size_t)b*SEQ*HS;
  const bf16* vtB = vtb + (size_t)b*HS*SEQ;

  auto loadKV = [&](int j) {
    const bf16* kt_ = kbB + (size_t)j*64*HS;
    const bf16* vt_ = vtB + j*64;
#pragma unroll
    for (int q = 0; q < 4; ++q) {
      kp[q]   = *(const bf16x8*)(kt_ + (size_t)r0*64        + hh + q*8);
      kp[4+q] = *(const bf16x8*)(kt_ + (size_t)(r0+32)*64   + hh + q*8);
      vp[q]   = *(const bf16x8*)(vt_ + (size_t)r0*SEQ       + hh + q*8);
      vp[4+q] = *(const bf16x8*)(vt_ + (size_t)(r0+32)*SEQ  + hh + q*8);
    }
  };
  auto writeKV = [&]() {
#pragma unroll
    for (int q = 0; q < 4; ++q) {
      *(bf16x8*)&Ks[w][r0][hh + q*8]      = kp[q];
      *(bf16x8*)&Ks[w][r0+32][hh + q*8]   = kp[4+q];
      *(bf16x8*)&VTs[w][r0][hh + q*8]     = vp[q];
      *(bf16x8*)&VTs[w][r0+32][hh + q*8]  = vp[4+q];
    }
  };

  int j = w;
  if (j < nkv) {
    loadKV(j);
    writeKV();
    while (true) {
      const int jn = j + 2;
      const bool more = jn < nkv;
      if (more) loadKV(jn);

      f32x4 s_acc[4];
#pragma unroll
      for (int na = 0; na < 4; ++na) {
        f32x4 z = vz;
        z = MFMA16(*(const bf16x8*)&Ks[w][16*na + m][g*8],      qf0, z);
        z = MFMA16(*(const bf16x8*)&Ks[w][16*na + m][32 + g*8], qf1, z);
        s_acc[na] = z;
      }
      if (j == nkv - 1) {   // causal mask: kv > q
        const int q_ = qt*16 + m;
#pragma unroll
        for (int na = 0; na < 4; ++na)
#pragma unroll
          for (int i = 0; i < 4; ++i)
            if (j*64 + 16*na + 4*g + i > q_) s_acc[na][i] = -INFINITY;
      }

      float mx = fmaxf(
        fmaxf(fmaxf(fmaxf(s_acc[0][0],s_acc[0][1]),fmaxf(s_acc[0][2],s_acc[0][3])),
              fmaxf(fmaxf(s_acc[1][0],s_acc[1][1]),fmaxf(s_acc[1][2],s_acc[1][3]))),
        fmaxf(fmaxf(fmaxf(s_acc[2][0],s_acc[2][1]),fmaxf(s_acc[2][2],s_acc[2][3])),
              fmaxf(fmaxf(s_acc[3][0],s_acc[3][1]),fmaxf(s_acc[3][2],s_acc[3][3]))));
      mx = fmaxf(mx, __shfl_xor(mx, 16));
      mx = fmaxf(mx, __shfl_xor(mx, 32));   // row max over all 64 kv
      float mnew = fmaxf(mrun, mx);
      float corr = __expf(mrun - mnew);
      mrun = mnew;
      float ts = 0.f;
#pragma unroll
      for (int na = 0; na < 4; ++na) {
        bf16x4 pk;
#pragma unroll
        for (int i = 0; i < 4; ++i) {
          float p = __expf(s_acc[na][i] - mnew);
          ts += p;
          pk[i] = (bf16)p;
        }
        *(bf16x4*)&Ps[w][m][16*na + 4*g] = pk;
      }
      ts += __shfl_xor(ts, 16);
      ts += __shfl_xor(ts, 32);
      lrun = lrun * corr + ts;
#pragma unroll
      for (int nd = 0; nd < 4; ++nd)
#pragma unroll
        for (int i = 0; i < 4; ++i) o_acc[nd][i] *= corr;

      bf16x8 pf0 = *(const bf16x8*)&Ps[w][m][g*8];
      bf16x8 pf1 = *(const bf16x8*)&Ps[w][m][32 + g*8];
#pragma unroll
      for (int nd = 0; nd < 4; ++nd) {
        o_acc[nd] = MFMA16(*(const bf16x8*)&VTs[w][16*nd + m][g*8],      pf0, o_acc[nd]);
        o_acc[nd] = MFMA16(*(const bf16x8*)&VTs[w][16*nd + m][32 + g*8], pf1, o_acc[nd]);
      }

      if (!more) break;
      writeKV();
      j = jn;
    }
  }

  float* PO = (float*)&Ks[w][0][0];    // 16 x 68 f32
  float* PM = (float*)&VTs[w][0][0];   // m[16], l[16]
#pragma unroll
  for (int nd = 0; nd < 4; ++nd)
    *(f32x4*)&PO[m*68 + 16*nd + 4*g] = o_acc[nd];
  if (g == 0) { PM[m] = mrun; PM[16 + m] = lrun; }
  __syncthreads();

  {
    const int r  = tid >> 3;
    const int c0 = (tid & 7) * 8;
    const float* O0 = (const float*)&Ks[0][0][0];
    const float* O1 = (const float*)&Ks[1][0][0];
    const float* M0 = (const float*)&VTs[0][0][0];
    const float* M1 = (const float*)&VTs[1][0][0];
    float m0 = M0[r], l0 = M0[16 + r];
    float m1 = M1[r], l1 = M1[16 + r];
    float mx = fmaxf(m0, m1);
    float s0 = __expf(m0 - mx), s1 = __expf(m1 - mx);
    float inv = 1.f / (s0*l0 + s1*l1);
    float4 x0 = *(const float4*)(O0 + r*68 + c0);
    float4 x1 = *(const float4*)(O0 + r*68 + c0 + 4);
    float4 y0 = *(const float4*)(O1 + r*68 + c0);
    float4 y1 = *(const float4*)(O1 + r*68 + c0 + 4);
    float4 o0, o1;
    o0.x=(x0.x*s0+y0.x*s1)*inv; o0.y=(x0.y*s0+y0.y*s1)*inv;
    o0.z=(x0.z*s0+y0.z*s1)*inv; o0.w=(x0.w*s0+y0.w*s1)*inv;
    o1.x=(x1.x*s0+y1.x*s1)*inv; o1.y=(x1.y*s0+y1.y*s1)*inv;
    o1.z=(x1.z*s0+y1.z*s1)*inv; o1.w=(x1.w*s0+y1.w*s1)*inv;
    float* op = out + ((size_t)b*SEQ + qt*16 + r) * HS + c0;
    *(float4*)(op)     = o0;
    *(float4*)(op + 4) = o1;
  }
}

extern "C" void kernel_launch(void* const* d_in, const int* in_sizes, int n_in,
                              void* d_out, int out_size, void* d_ws, size_t ws_size,
                              hipStream_t stream) {
  (void)in_sizes; (void)n_in; (void)out_size; (void)ws_size;
  const float* index  = (const float*)d_in[0];
  const float* memory = (const float*)d_in[1];
  const float* Wq     = (const float*)d_in[2];
  const float* Wk     = (const float*)d_in[3];
  const float* Wv     = (const float*)d_in[4];
  float* out = (float*)d_out;

  bf16* qb  = (bf16*)d_ws;                          // [NB*SEQ][64]
  bf16* kb  = qb  + (size_t)NB * SEQ * HS;          // [NB*SEQ][64]
  bf16* vtb = kb  + (size_t)NB * SEQ * HS;          // [NB][64][SEQ]
  bf16* wqb = vtb + (size_t)NB * SEQ * HS;          // [64][1024] (pre-scaled)
  bf16* wkb = wqb + (size_t)HS * NE;
  bf16* wvb = wkb + (size_t)HS * NE;

  wcvt_kernel<<<dim3(64), 256, 0, stream>>>(Wq, Wk, Wv, wqb, wkb, wvb);
  proj_kernel<<<dim3(768), 256, 0, stream>>>(index, memory, wqb, wkb, wvb, qb, kb, vtb);
  attn_kernel<<<dim3(128, 8), 128, 0, stream>>>(qb, kb, vtb, out);
}

// Round 13
// 85.088 us; speedup vs baseline: 1.1937x; 1.1937x over previous
//
#include <hip/hip_runtime.h>
#include <math.h>

typedef __bf16 bf16;
typedef __bf16 bf16x4 __attribute__((ext_vector_type(4)));
typedef __bf16 bf16x8 __attribute__((ext_vector_type(8)));
typedef float f32x4 __attribute__((ext_vector_type(4)));

#define MFMA16(a,b,c) __builtin_amdgcn_mfma_f32_16x16x32_bf16((a),(b),(c),0,0,0)

static constexpr int HS  = 64;    // head size
static constexpr int SEQ = 2048;  // sequence length
static constexpr int NE  = 1024;  // n_embed
static constexpr int NB  = 8;     // batch

__device__ __forceinline__ bf16x8 cvt8(float4 a, float4 b) {
  bf16x8 r;
  r[0]=(bf16)a.x; r[1]=(bf16)a.y; r[2]=(bf16)a.z; r[3]=(bf16)a.w;
  r[4]=(bf16)b.x; r[5]=(bf16)b.y; r[6]=(bf16)b.z; r[7]=(bf16)b.w;
  return r;
}

// ---- W f32 -> bf16 (Wq pre-scaled by 1/sqrt(64)) ----
__global__ __launch_bounds__(256) void wcvt_kernel(
    const float* __restrict__ Wq, const float* __restrict__ Wk,
    const float* __restrict__ Wv, bf16* __restrict__ wqb,
    bf16* __restrict__ wkb, bf16* __restrict__ wvb)
{
  int i = (blockIdx.x * 256 + threadIdx.x) * 4;   // 64 blocks -> 65536 elems
  float4 q = *(const float4*)(Wq + i);
  float4 k = *(const float4*)(Wk + i);
  float4 v = *(const float4*)(Wv + i);
  bf16x4 qo, ko, vo;
  qo[0]=(bf16)(q.x*0.125f); qo[1]=(bf16)(q.y*0.125f); qo[2]=(bf16)(q.z*0.125f); qo[3]=(bf16)(q.w*0.125f);
  ko[0]=(bf16)k.x; ko[1]=(bf16)k.y; ko[2]=(bf16)k.z; ko[3]=(bf16)k.w;
  vo[0]=(bf16)v.x; vo[1]=(bf16)v.y; vo[2]=(bf16)v.z; vo[3]=(bf16)v.w;
  *(bf16x4*)(wqb + i) = qo;
  *(bf16x4*)(wkb + i) = ko;
  *(bf16x4*)(wvb + i) = vo;
}

// ---- projection: W-STATIONARY in registers, X bf16 through LDS ----
// grid 768 x 256thr: blocks [0,256)=q, [256,512)=k, [512,768)=v — uniform.
// Wave w owns OUTPUT COLUMNS 16w..16w+15: its W fragments (16kt x 2kk x 16B
// = 128 VGPR) are preloaded ONCE -> zero per-step W traffic (was 4x-amplified
// LDS reads = 32 of R11's 72 LDS ops/step). Per step only X moves: reg-staged
// f32 -> cvt bf16 -> ds_write (8 instrs), A-read 32 instrs (4 waves x whole
// tile). lgkm-only barrier keeps global loads in flight across steps.
template<int TRANS>
__device__ __forceinline__ void proj_body(
    const float* __restrict__ X, const bf16* __restrict__ W,
    bf16* __restrict__ outN, bf16* __restrict__ outT, int slab,
    bf16* __restrict__ B0, bf16* __restrict__ B1)
{
  const int tid  = threadIdx.x;
  const int lane = tid & 63;
  const int w    = tid >> 6;
  const int m    = lane & 15;
  const int g    = lane >> 4;
  const int rowBase = slab * 64;
  const int srow = tid >> 2;          // staging row 0..63
  const int sc   = tid & 3;           // staging col-quarter

  // ---- W fragments: preload once (wave w -> W rows 16w..16w+15) ----
  bf16x8 wf[16][2];
  {
    const bf16* wp = W + (size_t)(16*w + m) * NE + g * 8;
#pragma unroll
    for (int kt = 0; kt < 16; ++kt) {
      wf[kt][0] = *(const bf16x8*)(wp + kt*64);
      wf[kt][1] = *(const bf16x8*)(wp + kt*64 + 32);
    }
  }

  const f32x4 vz = {0.f,0.f,0.f,0.f};
  f32x4 acc[4] = {vz, vz, vz, vz};    // acc[mt]: rows 16mt+4g+i, col 16w+m

  const float* xp = X + (size_t)(rowBase + srow) * NE + sc * 16;

  // two named X register sets (A: even steps, B: odd steps)
  float4 xaA, xbA, xcA, xdA;
  float4 xaB, xbB, xcB, xdB;

#define LOAD_X(S, kt) do {                                   \
    const float* _p = xp + (kt) * 64;                        \
    xa##S = *(const float4*)(_p);                            \
    xb##S = *(const float4*)(_p + 4);                        \
    xc##S = *(const float4*)(_p + 8);                        \
    xd##S = *(const float4*)(_p + 12);                       \
  } while (0)

  // LDS row = 128B (64 bf16), seg(16B) swizzle: seg' = seg ^ (row&7)
#define WRITE_X(S, Bd) do {                                              \
    *(bf16x8*)((char*)(Bd) + srow*128 + 16*((sc*2    ) ^ (srow & 7))) =  \
        cvt8(xa##S, xb##S);                                              \
    *(bf16x8*)((char*)(Bd) + srow*128 + 16*((sc*2 + 1) ^ (srow & 7))) =  \
        cvt8(xc##S, xd##S);                                              \
  } while (0)

  auto compute = [&](const bf16* Bc, int kt) {
#pragma unroll
    for (int kk = 0; kk < 2; ++kk)
#pragma unroll
      for (int mt = 0; mt < 4; ++mt) {
        const int arow = 16*mt + m;
        bf16x8 af = *(const bf16x8*)((const char*)Bc + arow*128 +
                                     16*((kk*4 + g) ^ (arow & 7)));
        acc[mt] = MFMA16(af, wf[kt][kk], acc[mt]);
      }
  };

  // prologue
  LOAD_X(A, 0);
  WRITE_X(A, B0);               // compiler waits vmcnt on set A only
  LOAD_X(B, 1);
  asm volatile("s_waitcnt lgkmcnt(0)" ::: "memory");
  __builtin_amdgcn_s_barrier();

#pragma unroll
  for (int t = 0; t < 16; ++t) {
    if (t + 2 < 16) {                       // refill the set just freed
      if (((t + 2) & 1) == 0) LOAD_X(A, t + 2);
      else                    LOAD_X(B, t + 2);
    }
    compute(((t & 1) == 0) ? B0 : B1, t);
    if (t + 1 < 16) {                       // stage next step's tile
      if (((t + 1) & 1) == 0) WRITE_X(A, B0);
      else                    WRITE_X(B, B1);
    }
    __builtin_amdgcn_sched_barrier(0);
    asm volatile("s_waitcnt lgkmcnt(0)" ::: "memory");  // DS only, not vmcnt
    __builtin_amdgcn_s_barrier();
    __builtin_amdgcn_sched_barrier(0);
  }
#undef LOAD_X
#undef WRITE_X

  // C/D: col = lane&15 -> output col 16w+m; row = 16mt + 4g + i  [m89]
#pragma unroll
  for (int mt = 0; mt < 4; ++mt)
#pragma unroll
    for (int i = 0; i < 4; ++i) {
      int row = rowBase + 16*mt + 4*g + i;
      int h   = 16*w + m;
      if (!TRANS)
        outN[(size_t)row * HS + h] = (bf16)acc[mt][i];
      else
        outT[((size_t)(row >> 11) * HS + h) * SEQ + (row & 2047)] =
            (bf16)acc[mt][i];
    }
}

__global__ __launch_bounds__(256, 2) void proj_kernel(
    const float* __restrict__ index, const float* __restrict__ memory,
    const bf16* __restrict__ wqb, const bf16* __restrict__ wkb,
    const bf16* __restrict__ wvb, bf16* __restrict__ qb,
    bf16* __restrict__ kb, bf16* __restrict__ vtb)
{
  __shared__ __align__(16) bf16 B0[64*64];   // 8 KB
  __shared__ __align__(16) bf16 B1[64*64];   // 8 KB  (16 KB total)
  const int bid = blockIdx.x;
  if (bid < 256)
    proj_body<0>(index,  wqb, qb, nullptr, bid,       B0, B1);
  else if (bid < 512)
    proj_body<0>(memory, wkb, kb, nullptr, bid - 256, B0, B1);
  else
    proj_body<1>(memory, wvb, nullptr, vtb, bid - 512, B0, B1);
}

// ---- flash attention: swapped-operand softmax (T12), unchanged from R11 ----
__global__ __launch_bounds__(128) void attn_kernel(
    const bf16* __restrict__ qb, const bf16* __restrict__ kb,
    const bf16* __restrict__ vtb, float* __restrict__ out)
{
  __shared__ __align__(16) bf16 Ks[2][64][72];    // per-wave K tile [kv][d]
  __shared__ __align__(16) bf16 VTs[2][64][72];   // per-wave V^T tile [d][kv]
  __shared__ __align__(16) bf16 Ps[2][16][72];    // per-wave P [q][kv]

  const int tid  = threadIdx.x;
  const int lane = tid & 63;
  const int w    = tid >> 6;
  const int m    = lane & 15;
  const int g    = lane >> 4;
  const int qt   = 127 - blockIdx.x;   // reversed: longest blocks first
  const int b    = blockIdx.y;
  const int nkv  = (qt >> 2) + 1;
  const int r0   = lane >> 1;
  const int hh   = (lane & 1) * 32;

  bf16x8 qf0 = *(const bf16x8*)(qb + ((size_t)b*SEQ + qt*16 + m)*HS + g*8);
  bf16x8 qf1 = *(const bf16x8*)(qb + ((size_t)b*SEQ + qt*16 + m)*HS + 32 + g*8);

  const f32x4 vz = {0.f,0.f,0.f,0.f};
  f32x4 o_acc[4] = {vz, vz, vz, vz};   // O^T[d=16nd+4g+i][q=m]
  float mrun = -INFINITY, lrun = 0.f;  // row-uniform state for q-row m

  bf16x8 kp[8], vp[8];
  const bf16* kbB = kb  + (size_t)b*SEQ*HS;
  const bf16* vtB = vtb + (size_t)b*HS*SEQ;

  auto loadKV = [&](int j) {
    const bf16* kt_ = kbB + (size_t)j*64*HS;
    const bf16* vt_ = vtB + j*64;
#pragma unroll
    for (int q = 0; q < 4; ++q) {
      kp[q]   = *(const bf16x8*)(kt_ + (size_t)r0*64        + hh + q*8);
      kp[4+q] = *(const bf16x8*)(kt_ + (size_t)(r0+32)*64   + hh + q*8);
      vp[q]   = *(const bf16x8*)(vt_ + (size_t)r0*SEQ       + hh + q*8);
      vp[4+q] = *(const bf16x8*)(vt_ + (size_t)(r0+32)*SEQ  + hh + q*8);
    }
  };
  auto writeKV = [&]() {
#pragma unroll
    for (int q = 0; q < 4; ++q) {
      *(bf16x8*)&Ks[w][r0][hh + q*8]      = kp[q];
      *(bf16x8*)&Ks[w][r0+32][hh + q*8]   = kp[4+q];
      *(bf16x8*)&VTs[w][r0][hh + q*8]     = vp[q];
      *(bf16x8*)&VTs[w][r0+32][hh + q*8]  = vp[4+q];
    }
  };

  int j = w;
  if (j < nkv) {
    loadKV(j);
    writeKV();
    while (true) {
      const int jn = j + 2;
      const bool more = jn < nkv;
      if (more) loadKV(jn);

      f32x4 s_acc[4];
#pragma unroll
      for (int na = 0; na < 4; ++na) {
        f32x4 z = vz;
        z = MFMA16(*(const bf16x8*)&Ks[w][16*na + m][g*8],      qf0, z);
        z = MFMA16(*(const bf16x8*)&Ks[w][16*na + m][32 + g*8], qf1, z);
        s_acc[na] = z;
      }
      if (j == nkv - 1) {   // causal mask: kv > q
        const int q_ = qt*16 + m;
#pragma unroll
        for (int na = 0; na < 4; ++na)
#pragma unroll
          for (int i = 0; i < 4; ++i)
            if (j*64 + 16*na + 4*g + i > q_) s_acc[na][i] = -INFINITY;
      }

      float mx = fmaxf(
        fmaxf(fmaxf(fmaxf(s_acc[0][0],s_acc[0][1]),fmaxf(s_acc[0][2],s_acc[0][3])),
              fmaxf(fmaxf(s_acc[1][0],s_acc[1][1]),fmaxf(s_acc[1][2],s_acc[1][3]))),
        fmaxf(fmaxf(fmaxf(s_acc[2][0],s_acc[2][1]),fmaxf(s_acc[2][2],s_acc[2][3])),
              fmaxf(fmaxf(s_acc[3][0],s_acc[3][1]),fmaxf(s_acc[3][2],s_acc[3][3]))));
      mx = fmaxf(mx, __shfl_xor(mx, 16));
      mx = fmaxf(mx, __shfl_xor(mx, 32));   // row max over all 64 kv
      float mnew = fmaxf(mrun, mx);
      float corr = __expf(mrun - mnew);
      mrun = mnew;
      float ts = 0.f;
#pragma unroll
      for (int na = 0; na < 4; ++na) {
        bf16x4 pk;
#pragma unroll
        for (int i = 0; i < 4; ++i) {
          float p = __expf(s_acc[na][i] - mnew);
          ts += p;
          pk[i] = (bf16)p;
        }
        *(bf16x4*)&Ps[w][m][16*na + 4*g] = pk;
      }
      ts += __shfl_xor(ts, 16);
      ts += __shfl_xor(ts, 32);
      lrun = lrun * corr + ts;
#pragma unroll
      for (int nd = 0; nd < 4; ++nd)
#pragma unroll
        for (int i = 0; i < 4; ++i) o_acc[nd][i] *= corr;

      bf16x8 pf0 = *(const bf16x8*)&Ps[w][m][g*8];
      bf16x8 pf1 = *(const bf16x8*)&Ps[w][m][32 + g*8];
#pragma unroll
      for (int nd = 0; nd < 4; ++nd) {
        o_acc[nd] = MFMA16(*(const bf16x8*)&VTs[w][16*nd + m][g*8],      pf0, o_acc[nd]);
        o_acc[nd] = MFMA16(*(const bf16x8*)&VTs[w][16*nd + m][32 + g*8], pf1, o_acc[nd]);
      }

      if (!more) break;
      writeKV();
      j = jn;
    }
  }

  float* PO = (float*)&Ks[w][0][0];    // 16 x 68 f32
  float* PM = (float*)&VTs[w][0][0];   // m[16], l[16]
#pragma unroll
  for (int nd = 0; nd < 4; ++nd)
    *(f32x4*)&PO[m*68 + 16*nd + 4*g] = o_acc[nd];
  if (g == 0) { PM[m] = mrun; PM[16 + m] = lrun; }
  __syncthreads();

  {
    const int r  = tid >> 3;
    const int c0 = (tid & 7) * 8;
    const float* O0 = (const float*)&Ks[0][0][0];
    const float* O1 = (const float*)&Ks[1][0][0];
    const float* M0 = (const float*)&VTs[0][0][0];
    const float* M1 = (const float*)&VTs[1][0][0];
    float m0 = M0[r], l0 = M0[16 + r];
    float m1 = M1[r], l1 = M1[16 + r];
    float mx = fmaxf(m0, m1);
    float s0 = __expf(m0 - mx), s1 = __expf(m1 - mx);
    float inv = 1.f / (s0*l0 + s1*l1);
    float4 x0 = *(const float4*)(O0 + r*68 + c0);
    float4 x1 = *(const float4*)(O0 + r*68 + c0 + 4);
    float4 y0 = *(const float4*)(O1 + r*68 + c0);
    float4 y1 = *(const float4*)(O1 + r*68 + c0 + 4);
    float4 o0, o1;
    o0.x=(x0.x*s0+y0.x*s1)*inv; o0.y=(x0.y*s0+y0.y*s1)*inv;
    o0.z=(x0.z*s0+y0.z*s1)*inv; o0.w=(x0.w*s0+y0.w*s1)*inv;
    o1.x=(x1.x*s0+y1.x*s1)*inv; o1.y=(x1.y*s0+y1.y*s1)*inv;
    o1.z=(x1.z*s0+y1.z*s1)*inv; o1.w=(x1.w*s0+y1.w*s1)*inv;
    float* op = out + ((size_t)b*SEQ + qt*16 + r) * HS + c0;
    *(float4*)(op)     = o0;
    *(float4*)(op + 4) = o1;
  }
}

extern "C" void kernel_launch(void* const* d_in, const int* in_sizes, int n_in,
                              void* d_out, int out_size, void* d_ws, size_t ws_size,
                              hipStream_t stream) {
  (void)in_sizes; (void)n_in; (void)out_size; (void)ws_size;
  const float* index  = (const float*)d_in[0];
  const float* memory = (const float*)d_in[1];
  const float* Wq     = (const float*)d_in[2];
  const float* Wk     = (const float*)d_in[3];
  const float* Wv     = (const float*)d_in[4];
  float* out = (float*)d_out;

  bf16* qb  = (bf16*)d_ws;                          // [NB*SEQ][64]
  bf16* kb  = qb  + (size_t)NB * SEQ * HS;          // [NB*SEQ][64]
  bf16* vtb = kb  + (size_t)NB * SEQ * HS;          // [NB][64][SEQ]
  bf16* wqb = vtb + (size_t)NB * SEQ * HS;          // [64][1024] (pre-scaled)
  bf16* wkb = wqb + (size_t)HS * NE;
  bf16* wvb = wkb + (size_t)HS * NE;

  wcvt_kernel<<<dim3(64), 256, 0, stream>>>(Wq, Wk, Wv, wqb, wkb, wvb);
  proj_kernel<<<dim3(768), 256, 0, stream>>>(index, memory, wqb, wkb, wvb, qb, kb, vtb);
  attn_kernel<<<dim3(128, 8), 128, 0, stream>>>(qb, kb, vtb, out);
}

// Round 14
// 80.357 us; speedup vs baseline: 1.2640x; 1.0589x over previous
//
#include <hip/hip_runtime.h>
#include <math.h>

typedef __bf16 bf16;
typedef __bf16 bf16x4 __attribute__((ext_vector_type(4)));
typedef __bf16 bf16x8 __attribute__((ext_vector_type(8)));
typedef float f32x4 __attribute__((ext_vector_type(4)));

#define MFMA16(a,b,c) __builtin_amdgcn_mfma_f32_16x16x32_bf16((a),(b),(c),0,0,0)

static constexpr int HS  = 64;    // head size
static constexpr int SEQ = 2048;  // sequence length
static constexpr int NE  = 1024;  // n_embed
static constexpr int NB  = 8;     // batch

__device__ __forceinline__ bf16x8 cvt8v(f32x4 a, f32x4 b) {
  bf16x8 r;
  r[0]=(bf16)a[0]; r[1]=(bf16)a[1]; r[2]=(bf16)a[2]; r[3]=(bf16)a[3];
  r[4]=(bf16)b[0]; r[5]=(bf16)b[1]; r[6]=(bf16)b[2]; r[7]=(bf16)b[3];
  return r;
}

// ---- W f32 -> bf16 (Wq pre-scaled by 1/sqrt(64)) ----
__global__ __launch_bounds__(256) void wcvt_kernel(
    const float* __restrict__ Wq, const float* __restrict__ Wk,
    const float* __restrict__ Wv, bf16* __restrict__ wqb,
    bf16* __restrict__ wkb, bf16* __restrict__ wvb)
{
  int i = (blockIdx.x * 256 + threadIdx.x) * 4;   // 64 blocks -> 65536 elems
  float4 q = *(const float4*)(Wq + i);
  float4 k = *(const float4*)(Wk + i);
  float4 v = *(const float4*)(Wv + i);
  bf16x4 qo, ko, vo;
  qo[0]=(bf16)(q.x*0.125f); qo[1]=(bf16)(q.y*0.125f); qo[2]=(bf16)(q.z*0.125f); qo[3]=(bf16)(q.w*0.125f);
  ko[0]=(bf16)k.x; ko[1]=(bf16)k.y; ko[2]=(bf16)k.z; ko[3]=(bf16)k.w;
  vo[0]=(bf16)v.x; vo[1]=(bf16)v.y; vo[2]=(bf16)v.z; vo[3]=(bf16)v.w;
  *(bf16x4*)(wqb + i) = qo;
  *(bf16x4*)(wkb + i) = ko;
  *(bf16x4*)(wvb + i) = vo;
}

// ---- projection: W-stationary in PINNED registers, X bf16 through LDS ----
// grid 768 x 256thr: [0,256)=q, [256,512)=k, [512,768)=v — uniform blocks.
// Wave w owns output cols 16w..16w+15. W frags live in 16 NAMED bf16x8 vars
// pinned by asm "+v" (opaque to the per-step "memory" clobber -> compiler
// CANNOT re-load them; R13's failure). One K-half at a time (64 VGPR),
// reloaded once at t=8. X: reg-staged f32 -> cvt bf16 -> swizzled LDS;
// lgkm-only barrier per step (global loads never drained).
template<int TRANS>
__device__ __forceinline__ void proj_body(
    const float* __restrict__ X, const bf16* __restrict__ W,
    bf16* __restrict__ outN, bf16* __restrict__ outT, int slab,
    bf16* __restrict__ B0, bf16* __restrict__ B1)
{
  const int tid  = threadIdx.x;
  const int lane = tid & 63;
  const int w    = tid >> 6;
  const int m    = lane & 15;
  const int g    = lane >> 4;
  const int rowBase = slab * 64;
  const int srow = tid >> 2;          // staging row 0..63
  const int sc   = tid & 3;           // staging col-quarter

  const bf16* wp = W + (size_t)(16*w + m) * NE + g * 8;
  bf16x8 w00,w01,w10,w11,w20,w21,w30,w31,w40,w41,w50,w51,w60,w61,w70,w71;

#define LOAD_WF(base) do {                                             \
    const bf16* _w = wp + (base) * 64;                                 \
    w00=*(const bf16x8*)(_w+0*64);  w01=*(const bf16x8*)(_w+0*64+32);  \
    w10=*(const bf16x8*)(_w+1*64);  w11=*(const bf16x8*)(_w+1*64+32);  \
    w20=*(const bf16x8*)(_w+2*64);  w21=*(const bf16x8*)(_w+2*64+32);  \
    w30=*(const bf16x8*)(_w+3*64);  w31=*(const bf16x8*)(_w+3*64+32);  \
    w40=*(const bf16x8*)(_w+4*64);  w41=*(const bf16x8*)(_w+4*64+32);  \
    w50=*(const bf16x8*)(_w+5*64);  w51=*(const bf16x8*)(_w+5*64+32);  \
    w60=*(const bf16x8*)(_w+6*64);  w61=*(const bf16x8*)(_w+6*64+32);  \
    w70=*(const bf16x8*)(_w+7*64);  w71=*(const bf16x8*)(_w+7*64+32);  \
  } while (0)

#define PIN_WF() asm volatile("" :                                      \
    "+v"(w00),"+v"(w01),"+v"(w10),"+v"(w11),"+v"(w20),"+v"(w21),        \
    "+v"(w30),"+v"(w31),"+v"(w40),"+v"(w41),"+v"(w50),"+v"(w51),        \
    "+v"(w60),"+v"(w61),"+v"(w70),"+v"(w71))

  const f32x4 vz = {0.f,0.f,0.f,0.f};
  f32x4 acc[4] = {vz, vz, vz, vz};    // acc[mt]: rows 16mt+4g+i, col 16w+m

  const float* xp = X + (size_t)(rowBase + srow) * NE + sc * 16;

  f32x4 xaA, xbA, xcA, xdA;           // set A: even kt
  f32x4 xaB, xbB, xcB, xdB;           // set B: odd kt

#define LOAD_X(S, kt) do {                                   \
    const float* _p = xp + (kt) * 64;                        \
    xa##S = *(const f32x4*)(_p);                             \
    xb##S = *(const f32x4*)(_p + 4);                         \
    xc##S = *(const f32x4*)(_p + 8);                         \
    xd##S = *(const f32x4*)(_p + 12);                        \
    asm volatile("" : "+v"(xa##S),"+v"(xb##S),"+v"(xc##S),"+v"(xd##S)); \
  } while (0)

  // LDS row = 128B (64 bf16), seg(16B) swizzle: seg' = seg ^ (row&7)
#define WRITE_X(S, Bd) do {                                              \
    *(bf16x8*)((char*)(Bd) + srow*128 + 16*((sc*2    ) ^ (srow & 7))) =  \
        cvt8v(xa##S, xb##S);                                             \
    *(bf16x8*)((char*)(Bd) + srow*128 + 16*((sc*2 + 1) ^ (srow & 7))) =  \
        cvt8v(xc##S, xd##S);                                             \
  } while (0)

#define COMPUTE(Bc, WFA, WFB) do {                                       \
    _Pragma("unroll")                                                    \
    for (int mt = 0; mt < 4; ++mt) {                                     \
      const int arow = 16*mt + m;                                        \
      bf16x8 af0 = *(const bf16x8*)((const char*)(Bc) + arow*128 +       \
                                    16*((0*4 + g) ^ (arow & 7)));        \
      acc[mt] = MFMA16(af0, WFA, acc[mt]);                               \
    }                                                                    \
    _Pragma("unroll")                                                    \
    for (int mt = 0; mt < 4; ++mt) {                                     \
      const int arow = 16*mt + m;                                        \
      bf16x8 af1 = *(const bf16x8*)((const char*)(Bc) + arow*128 +       \
                                    16*((1*4 + g) ^ (arow & 7)));        \
      acc[mt] = MFMA16(af1, WFB, acc[mt]);                               \
    }                                                                    \
  } while (0)

  // STEP T: refill load set, compute, stage next tile, lgkm-only barrier
#define STEP(T, WFA, WFB, SL, SW) do {                                   \
    if ((T) + 2 < 16) LOAD_X(SL, (T) + 2);                               \
    COMPUTE((((T) & 1) == 0) ? B0 : B1, WFA, WFB);                       \
    if ((T) + 1 < 16) {                                                  \
      if ((((T)+1) & 1) == 0) WRITE_X(SW, B0); else WRITE_X(SW, B1);     \
    }                                                                    \
    __builtin_amdgcn_sched_barrier(0);                                   \
    asm volatile("s_waitcnt lgkmcnt(0)" ::: "memory");                   \
    __builtin_amdgcn_s_barrier();                                        \
    __builtin_amdgcn_sched_barrier(0);                                   \
  } while (0)

  // prologue: W half-0 + X kt0/kt1
  LOAD_WF(0);  PIN_WF();
  LOAD_X(A, 0);
  WRITE_X(A, B0);               // precise vmcnt wait on set A only
  LOAD_X(B, 1);
  asm volatile("s_waitcnt lgkmcnt(0)" ::: "memory");
  __builtin_amdgcn_s_barrier();

  STEP(0,  w00,w01, A, B);
  STEP(1,  w10,w11, B, A);
  STEP(2,  w20,w21, A, B);
  STEP(3,  w30,w31, B, A);
  STEP(4,  w40,w41, A, B);
  STEP(5,  w50,w51, B, A);
  STEP(6,  w60,w61, A, B);
  STEP(7,  w70,w71, B, A);
  LOAD_WF(8);  PIN_WF();        // one-time reload (first use waits precisely)
  STEP(8,  w00,w01, A, B);
  STEP(9,  w10,w11, B, A);
  STEP(10, w20,w21, A, B);
  STEP(11, w30,w31, B, A);
  STEP(12, w40,w41, A, B);
  STEP(13, w50,w51, B, A);
  STEP(14, w60,w61, A, B);
  STEP(15, w70,w71, B, A);

#undef STEP
#undef COMPUTE
#undef WRITE_X
#undef LOAD_X
#undef PIN_WF
#undef LOAD_WF

  // C/D: col = lane&15 -> output col 16w+m; row = 16mt + 4g + i  [m89]
#pragma unroll
  for (int mt = 0; mt < 4; ++mt)
#pragma unroll
    for (int i = 0; i < 4; ++i) {
      int row = rowBase + 16*mt + 4*g + i;
      int h   = 16*w + m;
      if (!TRANS)
        outN[(size_t)row * HS + h] = (bf16)acc[mt][i];
      else
        outT[((size_t)(row >> 11) * HS + h) * SEQ + (row & 2047)] =
            (bf16)acc[mt][i];
    }
}

__global__ __launch_bounds__(256, 3) void proj_kernel(
    const float* __restrict__ index, const float* __restrict__ memory,
    const bf16* __restrict__ wqb, const bf16* __restrict__ wkb,
    const bf16* __restrict__ wvb, bf16* __restrict__ qb,
    bf16* __restrict__ kb, bf16* __restrict__ vtb)
{
  __shared__ __align__(16) bf16 B0[64*64];   // 8 KB
  __shared__ __align__(16) bf16 B1[64*64];   // 8 KB  (16 KB total)
  const int bid = blockIdx.x;
  if (bid < 256)
    proj_body<0>(index,  wqb, qb, nullptr, bid,       B0, B1);
  else if (bid < 512)
    proj_body<0>(memory, wkb, kb, nullptr, bid - 256, B0, B1);
  else
    proj_body<1>(memory, wvb, nullptr, vtb, bid - 512, B0, B1);
}

// ---- flash attention: swapped-operand softmax (T12), unchanged ----
__global__ __launch_bounds__(128) void attn_kernel(
    const bf16* __restrict__ qb, const bf16* __restrict__ kb,
    const bf16* __restrict__ vtb, float* __restrict__ out)
{
  __shared__ __align__(16) bf16 Ks[2][64][72];    // per-wave K tile [kv][d]
  __shared__ __align__(16) bf16 VTs[2][64][72];   // per-wave V^T tile [d][kv]
  __shared__ __align__(16) bf16 Ps[2][16][72];    // per-wave P [q][kv]

  const int tid  = threadIdx.x;
  const int lane = tid & 63;
  const int w    = tid >> 6;
  const int m    = lane & 15;
  const int g    = lane >> 4;
  const int qt   = 127 - blockIdx.x;   // reversed: longest blocks first
  const int b    = blockIdx.y;
  const int nkv  = (qt >> 2) + 1;
  const int r0   = lane >> 1;
  const int hh   = (lane & 1) * 32;

  bf16x8 qf0 = *(const bf16x8*)(qb + ((size_t)b*SEQ + qt*16 + m)*HS + g*8);
  bf16x8 qf1 = *(const bf16x8*)(qb + ((size_t)b*SEQ + qt*16 + m)*HS + 32 + g*8);

  const f32x4 vz = {0.f,0.f,0.f,0.f};
  f32x4 o_acc[4] = {vz, vz, vz, vz};   // O^T[d=16nd+4g+i][q=m]
  float mrun = -INFINITY, lrun = 0.f;  // row-uniform state for q-row m

  bf16x8 kp[8], vp[8];
  const bf16* kbB = kb  + (size_t)b*SEQ*HS;
  const bf16* vtB = vtb + (size_t)b*HS*SEQ;

  auto loadKV = [&](int j) {
    const bf16* kt_ = kbB + (size_t)j*64*HS;
    const bf16* vt_ = vtB + j*64;
#pragma unroll
    for (int q = 0; q < 4; ++q) {
      kp[q]   = *(const bf16x8*)(kt_ + (size_t)r0*64        + hh + q*8);
      kp[4+q] = *(const bf16x8*)(kt_ + (size_t)(r0+32)*64   + hh + q*8);
      vp[q]   = *(const bf16x8*)(vt_ + (size_t)r0*SEQ       + hh + q*8);
      vp[4+q] = *(const bf16x8*)(vt_ + (size_t)(r0+32)*SEQ  + hh + q*8);
    }
  };
  auto writeKV = [&]() {
#pragma unroll
    for (int q = 0; q < 4; ++q) {
      *(bf16x8*)&Ks[w][r0][hh + q*8]      = kp[q];
      *(bf16x8*)&Ks[w][r0+32][hh + q*8]   = kp[4+q];
      *(bf16x8*)&VTs[w][r0][hh + q*8]     = vp[q];
      *(bf16x8*)&VTs[w][r0+32][hh + q*8]  = vp[4+q];
    }
  };

  int j = w;
  if (j < nkv) {
    loadKV(j);
    writeKV();
    while (true) {
      const int jn = j + 2;
      const bool more = jn < nkv;
      if (more) loadKV(jn);

      f32x4 s_acc[4];
#pragma unroll
      for (int na = 0; na < 4; ++na) {
        f32x4 z = vz;
        z = MFMA16(*(const bf16x8*)&Ks[w][16*na + m][g*8],      qf0, z);
        z = MFMA16(*(const bf16x8*)&Ks[w][16*na + m][32 + g*8], qf1, z);
        s_acc[na] = z;
      }
      if (j == nkv - 1) {   // causal mask: kv > q
        const int q_ = qt*16 + m;
#pragma unroll
        for (int na = 0; na < 4; ++na)
#pragma unroll
          for (int i = 0; i < 4; ++i)
            if (j*64 + 16*na + 4*g + i > q_) s_acc[na][i] = -INFINITY;
      }

      float mx = fmaxf(
        fmaxf(fmaxf(fmaxf(s_acc[0][0],s_acc[0][1]),fmaxf(s_acc[0][2],s_acc[0][3])),
              fmaxf(fmaxf(s_acc[1][0],s_acc[1][1]),fmaxf(s_acc[1][2],s_acc[1][3]))),
        fmaxf(fmaxf(fmaxf(s_acc[2][0],s_acc[2][1]),fmaxf(s_acc[2][2],s_acc[2][3])),
              fmaxf(fmaxf(s_acc[3][0],s_acc[3][1]),fmaxf(s_acc[3][2],s_acc[3][3]))));
      mx = fmaxf(mx, __shfl_xor(mx, 16));
      mx = fmaxf(mx, __shfl_xor(mx, 32));   // row max over all 64 kv
      float mnew = fmaxf(mrun, mx);
      float corr = __expf(mrun - mnew);
      mrun = mnew;
      float ts = 0.f;
#pragma unroll
      for (int na = 0; na < 4; ++na) {
        bf16x4 pk;
#pragma unroll
        for (int i = 0; i < 4; ++i) {
          float p = __expf(s_acc[na][i] - mnew);
          ts += p;
          pk[i] = (bf16)p;
        }
        *(bf16x4*)&Ps[w][m][16*na + 4*g] = pk;
      }
      ts += __shfl_xor(ts, 16);
      ts += __shfl_xor(ts, 32);
      lrun = lrun * corr + ts;
#pragma unroll
      for (int nd = 0; nd < 4; ++nd)
#pragma unroll
        for (int i = 0; i < 4; ++i) o_acc[nd][i] *= corr;

      bf16x8 pf0 = *(const bf16x8*)&Ps[w][m][g*8];
      bf16x8 pf1 = *(const bf16x8*)&Ps[w][m][32 + g*8];
#pragma unroll
      for (int nd = 0; nd < 4; ++nd) {
        o_acc[nd] = MFMA16(*(const bf16x8*)&VTs[w][16*nd + m][g*8],      pf0, o_acc[nd]);
        o_acc[nd] = MFMA16(*(const bf16x8*)&VTs[w][16*nd + m][32 + g*8], pf1, o_acc[nd]);
      }

      if (!more) break;
      writeKV();
      j = jn;
    }
  }

  float* PO = (float*)&Ks[w][0][0];    // 16 x 68 f32
  float* PM = (float*)&VTs[w][0][0];   // m[16], l[16]
#pragma unroll
  for (int nd = 0; nd < 4; ++nd)
    *(f32x4*)&PO[m*68 + 16*nd + 4*g] = o_acc[nd];
  if (g == 0) { PM[m] = mrun; PM[16 + m] = lrun; }
  __syncthreads();

  {
    const int r  = tid >> 3;
    const int c0 = (tid & 7) * 8;
    const float* O0 = (const float*)&Ks[0][0][0];
    const float* O1 = (const float*)&Ks[1][0][0];
    const float* M0 = (const float*)&VTs[0][0][0];
    const float* M1 = (const float*)&VTs[1][0][0];
    float m0 = M0[r], l0 = M0[16 + r];
    float m1 = M1[r], l1 = M1[16 + r];
    float mx = fmaxf(m0, m1);
    float s0 = __expf(m0 - mx), s1 = __expf(m1 - mx);
    float inv = 1.f / (s0*l0 + s1*l1);
    float4 x0 = *(const float4*)(O0 + r*68 + c0);
    float4 x1 = *(const float4*)(O0 + r*68 + c0 + 4);
    float4 y0 = *(const float4*)(O1 + r*68 + c0);
    float4 y1 = *(const float4*)(O1 + r*68 + c0 + 4);
    float4 o0, o1;
    o0.x=(x0.x*s0+y0.x*s1)*inv; o0.y=(x0.y*s0+y0.y*s1)*inv;
    o0.z=(x0.z*s0+y0.z*s1)*inv; o0.w=(x0.w*s0+y0.w*s1)*inv;
    o1.x=(x1.x*s0+y1.x*s1)*inv; o1.y=(x1.y*s0+y1.y*s1)*inv;
    o1.z=(x1.z*s0+y1.z*s1)*inv; o1.w=(x1.w*s0+y1.w*s1)*inv;
    float* op = out + ((size_t)b*SEQ + qt*16 + r) * HS + c0;
    *(float4*)(op)     = o0;
    *(float4*)(op + 4) = o1;
  }
}

extern "C" void kernel_launch(void* const* d_in, const int* in_sizes, int n_in,
                              void* d_out, int out_size, void* d_ws, size_t ws_size,
                              hipStream_t stream) {
  (void)in_sizes; (void)n_in; (void)out_size; (void)ws_size;
  const float* index  = (const float*)d_in[0];
  const float* memory = (const float*)d_in[1];
  const float* Wq     = (const float*)d_in[2];
  const float* Wk     = (const float*)d_in[3];
  const float* Wv     = (const float*)d_in[4];
  float* out = (float*)d_out;

  bf16* qb  = (bf16*)d_ws;                          // [NB*SEQ][64]
  bf16* kb  = qb  + (size_t)NB * SEQ * HS;          // [NB*SEQ][64]
  bf16* vtb = kb  + (size_t)NB * SEQ * HS;          // [NB][64][SEQ]
  bf16* wqb = vtb + (size_t)NB * SEQ * HS;          // [64][1024] (pre-scaled)
  bf16* wkb = wqb + (size_t)HS * NE;
  bf16* wvb = wkb + (size_t)HS * NE;

  wcvt_kernel<<<dim3(64), 256, 0, stream>>>(Wq, Wk, Wv, wqb, wkb, wvb);
  proj_kernel<<<dim3(768), 256, 0, stream>>>(index, memory, wqb, wkb, wvb, qb, kb, vtb);
  attn_kernel<<<dim3(128, 8), 128, 0, stream>>>(qb, kb, vtb, out);
}

// Round 15
// 75.085 us; speedup vs baseline: 1.3527x; 1.0702x over previous
//
#include <hip/hip_runtime.h>
#include <math.h>

typedef __bf16 bf16;
typedef __bf16 bf16x4 __attribute__((ext_vector_type(4)));
typedef __bf16 bf16x8 __attribute__((ext_vector_type(8)));
typedef float f32x4 __attribute__((ext_vector_type(4)));

#define MFMA16(a,b,c) __builtin_amdgcn_mfma_f32_16x16x32_bf16((a),(b),(c),0,0,0)

static constexpr int HS  = 64;    // head size
static constexpr int SEQ = 2048;  // sequence length
static constexpr int NE  = 1024;  // n_embed
static constexpr int NB  = 8;     // batch

__device__ __forceinline__ bf16x8 cvt8v(f32x4 a, f32x4 b) {
  bf16x8 r;
  r[0]=(bf16)a[0]; r[1]=(bf16)a[1]; r[2]=(bf16)a[2]; r[3]=(bf16)a[3];
  r[4]=(bf16)b[0]; r[5]=(bf16)b[1]; r[6]=(bf16)b[2]; r[7]=(bf16)b[3];
  return r;
}

// ---- W f32 -> bf16 (Wq pre-scaled by 1/sqrt(64)) ----
__global__ __launch_bounds__(256) void wcvt_kernel(
    const float* __restrict__ Wq, const float* __restrict__ Wk,
    const float* __restrict__ Wv, bf16* __restrict__ wqb,
    bf16* __restrict__ wkb, bf16* __restrict__ wvb)
{
  int i = (blockIdx.x * 256 + threadIdx.x) * 4;   // 64 blocks -> 65536 elems
  float4 q = *(const float4*)(Wq + i);
  float4 k = *(const float4*)(Wk + i);
  float4 v = *(const float4*)(Wv + i);
  bf16x4 qo, ko, vo;
  qo[0]=(bf16)(q.x*0.125f); qo[1]=(bf16)(q.y*0.125f); qo[2]=(bf16)(q.z*0.125f); qo[3]=(bf16)(q.w*0.125f);
  ko[0]=(bf16)k.x; ko[1]=(bf16)k.y; ko[2]=(bf16)k.z; ko[3]=(bf16)k.w;
  vo[0]=(bf16)v.x; vo[1]=(bf16)v.y; vo[2]=(bf16)v.z; vo[3]=(bf16)v.w;
  *(bf16x4*)(wqb + i) = qo;
  *(bf16x4*)(wkb + i) = ko;
  *(bf16x4*)(wvb + i) = vo;
}

// ---- projection: traffic-minimal. 256 blocks x 512 thr (8 waves). ----
// Even bid: Q block — 128-row index slab, 8 waves x 16 rows, Wq only.
// Odd  bid: KV block — 128-row memory slab staged ONCE; waves 0-3 -> k,
//           waves 4-7 -> v (32 rows each). Memory is read once (was twice).
// 128-row slabs halve W re-staging. X reg-staged f32 -> bf16 -> swizzled LDS
// (16KB/buf); lgkm-only barrier per step (global loads never drained).
// LDS 64KB -> 2 blocks/CU (16 waves).
template<int KV>
__device__ __forceinline__ void proj_body(
    const float* __restrict__ X, const bf16* __restrict__ W0,
    const bf16* __restrict__ W1, bf16* __restrict__ outA,
    bf16* __restrict__ outVT, int slab,
    bf16* __restrict__ Xs0, bf16* __restrict__ Xs1,
    bf16* __restrict__ Ws0, bf16* __restrict__ Ws1)   // Ws*: [2][64*64]
{
  const int tid  = threadIdx.x;
  const int lane = tid & 63;
  const int w    = tid >> 6;          // 0..7
  const int m    = lane & 15;
  const int g    = lane >> 4;
  const int rowBase = slab * 128;
  const int srow = tid >> 2;          // X staging row 0..127
  const int sc   = tid & 3;           // X staging col-quarter
  const int wrow = tid >> 3;          // W staging row 0..63
  const int wseg = tid & 7;           // W staging 16B-seg

  const float* xp  = X  + (size_t)(rowBase + srow) * NE + sc * 16;
  const bf16*  w0p = W0 + (size_t)wrow * NE + wseg * 8;
  const bf16*  w1p = KV ? (W1 + (size_t)wrow * NE + wseg * 8) : nullptr;

  const f32x4 vz = {0.f,0.f,0.f,0.f};
  f32x4 acc0[4] = {vz, vz, vz, vz};   // Q: n-tiles | KV: rt=0 n-tiles
  f32x4 acc1[4] = {vz, vz, vz, vz};   // KV: rt=1 n-tiles (DCE'd for Q)

  f32x4 xaA, xbA, xcA, xdA;  bf16x8 wkA, wvA;   // set A: even kt
  f32x4 xaB, xbB, xcB, xdB;  bf16x8 wkB, wvB;   // set B: odd kt

#define LOAD_T(S, kt) do {                                              \
    const float* _p = xp + (kt) * 64;                                   \
    xa##S = *(const f32x4*)(_p);      xb##S = *(const f32x4*)(_p + 4);  \
    xc##S = *(const f32x4*)(_p + 8);  xd##S = *(const f32x4*)(_p + 12); \
    wk##S = *(const bf16x8*)(w0p + (kt) * 64);                          \
    if (KV) wv##S = *(const bf16x8*)(w1p + (kt) * 64);                  \
    asm volatile("" : "+v"(xa##S),"+v"(xb##S),"+v"(xc##S),"+v"(xd##S)); \
  } while (0)

  // X LDS row = 128B (64 bf16); 16B-seg swizzle: seg' = seg ^ (row&7)
#define WRITE_T(S, Xd, Wk_, Wv_) do {                                     \
    *(bf16x8*)((char*)(Xd) + srow*128 + 16*((sc*2    ) ^ (srow & 7))) =   \
        cvt8v(xa##S, xb##S);                                              \
    *(bf16x8*)((char*)(Xd) + srow*128 + 16*((sc*2 + 1) ^ (srow & 7))) =   \
        cvt8v(xc##S, xd##S);                                              \
    *(bf16x8*)((char*)(Wk_) + wrow*128 + 16*(wseg ^ (wrow & 7))) = wk##S; \
    if (KV)                                                               \
      *(bf16x8*)((char*)(Wv_) + wrow*128 + 16*(wseg ^ (wrow & 7))) = wv##S;\
  } while (0)

  auto compute = [&](const bf16* Xd, const bf16* Wk_, const bf16* Wv_) {
    if (!KV) {
      const int arow = 16*w + m;
#pragma unroll
      for (int kk = 0; kk < 2; ++kk) {
        bf16x8 af = *(const bf16x8*)((const char*)Xd + arow*128 +
                                     16*((kk*4 + g) ^ (arow & 7)));
#pragma unroll
        for (int n = 0; n < 4; ++n) {
          const int col = 16*n + m;
          bf16x8 b0 = *(const bf16x8*)((const char*)Wk_ + col*128 +
                                       16*((kk*4 + g) ^ (col & 7)));
          acc0[n] = MFMA16(af, b0, acc0[n]);
        }
      }
    } else {
      const int wk_ = w & 3;                 // row-group within role
      const bf16* Wd = (w < 4) ? Wk_ : Wv_;  // waves 0-3: k, 4-7: v
#pragma unroll
      for (int rt = 0; rt < 2; ++rt) {
        const int arow = 32*wk_ + 16*rt + m;
#pragma unroll
        for (int kk = 0; kk < 2; ++kk) {
          bf16x8 af = *(const bf16x8*)((const char*)Xd + arow*128 +
                                       16*((kk*4 + g) ^ (arow & 7)));
#pragma unroll
          for (int n = 0; n < 4; ++n) {
            const int col = 16*n + m;
            bf16x8 b0 = *(const bf16x8*)((const char*)Wd + col*128 +
                                         16*((kk*4 + g) ^ (col & 7)));
            if (rt == 0) acc0[n] = MFMA16(af, b0, acc0[n]);
            else         acc1[n] = MFMA16(af, b0, acc1[n]);
          }
        }
      }
    }
  };

  // prologue: kt0 -> A, write buf0 (precise vmcnt wait on A), kt1 -> B
  LOAD_T(A, 0);
  WRITE_T(A, Xs0, Ws0, Ws0 + 64*64);
  LOAD_T(B, 1);
  asm volatile("s_waitcnt lgkmcnt(0)" ::: "memory");
  __builtin_amdgcn_s_barrier();

#pragma unroll
  for (int t = 0; t < 16; ++t) {
    // compute(buf t&1): reads tile staged at step t-1 (ordered by barrier)
    if ((t & 1) == 0) compute(Xs0, Ws0, Ws0 + 64*64);
    else              compute(Xs1, Ws1, Ws1 + 64*64);
    if (t + 2 < 16) {                       // refill the set freed at t-1
      if (((t + 2) & 1) == 0) LOAD_T(A, t + 2);
      else                    LOAD_T(B, t + 2);
    }
    if (t + 1 < 16) {                       // stage next tile (buf (t+1)&1:
      if (((t + 1) & 1) == 0) WRITE_T(A, Xs0, Ws0, Ws0 + 64*64);  // last read
      else                    WRITE_T(B, Xs1, Ws1, Ws1 + 64*64);  // at t-1)
    }
    __builtin_amdgcn_sched_barrier(0);
    asm volatile("s_waitcnt lgkmcnt(0)" ::: "memory");  // DS only, not vmcnt
    __builtin_amdgcn_s_barrier();
    __builtin_amdgcn_sched_barrier(0);
  }
#undef LOAD_T
#undef WRITE_T

  // C/D: col = lane&15, row = 4*(lane>>4)+i  [m89-verified]
  if (!KV) {
#pragma unroll
    for (int n = 0; n < 4; ++n)
#pragma unroll
      for (int i = 0; i < 4; ++i) {
        int row = rowBase + 16*w + 4*g + i;
        outA[(size_t)row * HS + 16*n + m] = (bf16)acc0[n][i];
      }
  } else if (w < 4) {                       // k -> kb (row-major)
#pragma unroll
    for (int rt = 0; rt < 2; ++rt)
#pragma unroll
      for (int n = 0; n < 4; ++n)
#pragma unroll
        for (int i = 0; i < 4; ++i) {
          int row = rowBase + 32*(w & 3) + 16*rt + 4*g + i;
          f32x4& a = rt ? acc1[n] : acc0[n];
          outA[(size_t)row * HS + 16*n + m] = (bf16)a[i];
        }
  } else {                                  // v -> vtb (transposed)
#pragma unroll
    for (int rt = 0; rt < 2; ++rt)
#pragma unroll
      for (int n = 0; n < 4; ++n)
#pragma unroll
        for (int i = 0; i < 4; ++i) {
          int row = rowBase + 32*(w & 3) + 16*rt + 4*g + i;
          int h   = 16*n + m;
          f32x4& a = rt ? acc1[n] : acc0[n];
          outVT[((size_t)(row >> 11) * HS + h) * SEQ + (row & 2047)] =
              (bf16)a[i];
        }
  }
}

__global__ __launch_bounds__(512, 4) void proj_kernel(
    const float* __restrict__ index, const float* __restrict__ memory,
    const bf16* __restrict__ wqb, const bf16* __restrict__ wkb,
    const bf16* __restrict__ wvb, bf16* __restrict__ qb,
    bf16* __restrict__ kb, bf16* __restrict__ vtb)
{
  __shared__ __align__(16) bf16 Xs0[128*64], Xs1[128*64];    // 16KB each
  __shared__ __align__(16) bf16 Ws0[2*64*64], Ws1[2*64*64];  // 16KB each: 64KB
  const int bid  = blockIdx.x;
  const int slab = bid >> 1;               // 0..127
  if ((bid & 1) == 0)
    proj_body<0>(index,  wqb, nullptr, qb, nullptr, slab, Xs0, Xs1, Ws0, Ws1);
  else
    proj_body<1>(memory, wkb, wvb,     kb, vtb,     slab, Xs0, Xs1, Ws0, Ws1);
}

// ---- flash attention: swapped-operand softmax (T12), unchanged ----
__global__ __launch_bounds__(128) void attn_kernel(
    const bf16* __restrict__ qb, const bf16* __restrict__ kb,
    const bf16* __restrict__ vtb, float* __restrict__ out)
{
  __shared__ __align__(16) bf16 Ks[2][64][72];    // per-wave K tile [kv][d]
  __shared__ __align__(16) bf16 VTs[2][64][72];   // per-wave V^T tile [d][kv]
  __shared__ __align__(16) bf16 Ps[2][16][72];    // per-wave P [q][kv]

  const int tid  = threadIdx.x;
  const int lane = tid & 63;
  const int w    = tid >> 6;
  const int m    = lane & 15;
  const int g    = lane >> 4;
  const int qt   = 127 - blockIdx.x;   // reversed: longest blocks first
  const int b    = blockIdx.y;
  const int nkv  = (qt >> 2) + 1;
  const int r0   = lane >> 1;
  const int hh   = (lane & 1) * 32;

  bf16x8 qf0 = *(const bf16x8*)(qb + ((size_t)b*SEQ + qt*16 + m)*HS + g*8);
  bf16x8 qf1 = *(const bf16x8*)(qb + ((size_t)b*SEQ + qt*16 + m)*HS + 32 + g*8);

  const f32x4 vz = {0.f,0.f,0.f,0.f};
  f32x4 o_acc[4] = {vz, vz, vz, vz};   // O^T[d=16nd+4g+i][q=m]
  float mrun = -INFINITY, lrun = 0.f;  // row-uniform state for q-row m

  bf16x8 kp[8], vp[8];
  const bf16* kbB = kb  + (size_t)b*SEQ*HS;
  const bf16* vtB = vtb + (size_t)b*HS*SEQ;

  auto loadKV = [&](int j) {
    const bf16* kt_ = kbB + (size_t)j*64*HS;
    const bf16* vt_ = vtB + j*64;
#pragma unroll
    for (int q = 0; q < 4; ++q) {
      kp[q]   = *(const bf16x8*)(kt_ + (size_t)r0*64        + hh + q*8);
      kp[4+q] = *(const bf16x8*)(kt_ + (size_t)(r0+32)*64   + hh + q*8);
      vp[q]   = *(const bf16x8*)(vt_ + (size_t)r0*SEQ       + hh + q*8);
      vp[4+q] = *(const bf16x8*)(vt_ + (size_t)(r0+32)*SEQ  + hh + q*8);
    }
  };
  auto writeKV = [&]() {
#pragma unroll
    for (int q = 0; q < 4; ++q) {
      *(bf16x8*)&Ks[w][r0][hh + q*8]      = kp[q];
      *(bf16x8*)&Ks[w][r0+32][hh + q*8]   = kp[4+q];
      *(bf16x8*)&VTs[w][r0][hh + q*8]     = vp[q];
      *(bf16x8*)&VTs[w][r0+32][hh + q*8]  = vp[4+q];
    }
  };

  int j = w;
  if (j < nkv) {
    loadKV(j);
    writeKV();
    while (true) {
      const int jn = j + 2;
      const bool more = jn < nkv;
      if (more) loadKV(jn);

      f32x4 s_acc[4];
#pragma unroll
      for (int na = 0; na < 4; ++na) {
        f32x4 z = vz;
        z = MFMA16(*(const bf16x8*)&Ks[w][16*na + m][g*8],      qf0, z);
        z = MFMA16(*(const bf16x8*)&Ks[w][16*na + m][32 + g*8], qf1, z);
        s_acc[na] = z;
      }
      if (j == nkv - 1) {   // causal mask: kv > q
        const int q_ = qt*16 + m;
#pragma unroll
        for (int na = 0; na < 4; ++na)
#pragma unroll
          for (int i = 0; i < 4; ++i)
            if (j*64 + 16*na + 4*g + i > q_) s_acc[na][i] = -INFINITY;
      }

      float mx = fmaxf(
        fmaxf(fmaxf(fmaxf(s_acc[0][0],s_acc[0][1]),fmaxf(s_acc[0][2],s_acc[0][3])),
              fmaxf(fmaxf(s_acc[1][0],s_acc[1][1]),fmaxf(s_acc[1][2],s_acc[1][3]))),
        fmaxf(fmaxf(fmaxf(s_acc[2][0],s_acc[2][1]),fmaxf(s_acc[2][2],s_acc[2][3])),
              fmaxf(fmaxf(s_acc[3][0],s_acc[3][1]),fmaxf(s_acc[3][2],s_acc[3][3]))));
      mx = fmaxf(mx, __shfl_xor(mx, 16));
      mx = fmaxf(mx, __shfl_xor(mx, 32));   // row max over all 64 kv
      float mnew = fmaxf(mrun, mx);
      float corr = __expf(mrun - mnew);
      mrun = mnew;
      float ts = 0.f;
#pragma unroll
      for (int na = 0; na < 4; ++na) {
        bf16x4 pk;
#pragma unroll
        for (int i = 0; i < 4; ++i) {
          float p = __expf(s_acc[na][i] - mnew);
          ts += p;
          pk[i] = (bf16)p;
        }
        *(bf16x4*)&Ps[w][m][16*na + 4*g] = pk;
      }
      ts += __shfl_xor(ts, 16);
      ts += __shfl_xor(ts, 32);
      lrun = lrun * corr + ts;
#pragma unroll
      for (int nd = 0; nd < 4; ++nd)
#pragma unroll
        for (int i = 0; i < 4; ++i) o_acc[nd][i] *= corr;

      bf16x8 pf0 = *(const bf16x8*)&Ps[w][m][g*8];
      bf16x8 pf1 = *(const bf16x8*)&Ps[w][m][32 + g*8];
#pragma unroll
      for (int nd = 0; nd < 4; ++nd) {
        o_acc[nd] = MFMA16(*(const bf16x8*)&VTs[w][16*nd + m][g*8],      pf0, o_acc[nd]);
        o_acc[nd] = MFMA16(*(const bf16x8*)&VTs[w][16*nd + m][32 + g*8], pf1, o_acc[nd]);
      }

      if (!more) break;
      writeKV();
      j = jn;
    }
  }

  float* PO = (float*)&Ks[w][0][0];    // 16 x 68 f32
  float* PM = (float*)&VTs[w][0][0];   // m[16], l[16]
#pragma unroll
  for (int nd = 0; nd < 4; ++nd)
    *(f32x4*)&PO[m*68 + 16*nd + 4*g] = o_acc[nd];
  if (g == 0) { PM[m] = mrun; PM[16 + m] = lrun; }
  __syncthreads();

  {
    const int r  = tid >> 3;
    const int c0 = (tid & 7) * 8;
    const float* O0 = (const float*)&Ks[0][0][0];
    const float* O1 = (const float*)&Ks[1][0][0];
    const float* M0 = (const float*)&VTs[0][0][0];
    const float* M1 = (const float*)&VTs[1][0][0];
    float m0 = M0[r], l0 = M0[16 + r];
    float m1 = M1[r], l1 = M1[16 + r];
    float mx = fmaxf(m0, m1);
    float s0 = __expf(m0 - mx), s1 = __expf(m1 - mx);
    float inv = 1.f / (s0*l0 + s1*l1);
    float4 x0 = *(const float4*)(O0 + r*68 + c0);
    float4 x1 = *(const float4*)(O0 + r*68 + c0 + 4);
    float4 y0 = *(const float4*)(O1 + r*68 + c0);
    float4 y1 = *(const float4*)(O1 + r*68 + c0 + 4);
    float4 o0, o1;
    o0.x=(x0.x*s0+y0.x*s1)*inv; o0.y=(x0.y*s0+y0.y*s1)*inv;
    o0.z=(x0.z*s0+y0.z*s1)*inv; o0.w=(x0.w*s0+y0.w*s1)*inv;
    o1.x=(x1.x*s0+y1.x*s1)*inv; o1.y=(x1.y*s0+y1.y*s1)*inv;
    o1.z=(x1.z*s0+y1.z*s1)*inv; o1.w=(x1.w*s0+y1.w*s1)*inv;
    float* op = out + ((size_t)b*SEQ + qt*16 + r) * HS + c0;
    *(float4*)(op)     = o0;
    *(float4*)(op + 4) = o1;
  }
}

extern "C" void kernel_launch(void* const* d_in, const int* in_sizes, int n_in,
                              void* d_out, int out_size, void* d_ws, size_t ws_size,
                              hipStream_t stream) {
  (void)in_sizes; (void)n_in; (void)out_size; (void)ws_size;
  const float* index  = (const float*)d_in[0];
  const float* memory = (const float*)d_in[1];
  const float* Wq     = (const float*)d_in[2];
  const float* Wk     = (const float*)d_in[3];
  const float* Wv     = (const float*)d_in[4];
  float* out = (float*)d_out;

  bf16* qb  = (bf16*)d_ws;                          // [NB*SEQ][64]
  bf16* kb  = qb  + (size_t)NB * SEQ * HS;          // [NB*SEQ][64]
  bf16* vtb = kb  + (size_t)NB * SEQ * HS;          // [NB][64][SEQ]
  bf16* wqb = vtb + (size_t)NB * SEQ * HS;          // [64][1024] (pre-scaled)
  bf16* wkb = wqb + (size_t)HS * NE;
  bf16* wvb = wkb + (size_t)HS * NE;

  wcvt_kernel<<<dim3(64), 256, 0, stream>>>(Wq, Wk, Wv, wqb, wkb, wvb);
  proj_kernel<<<dim3(256), 512, 0, stream>>>(index, memory, wqb, wkb, wvb, qb, kb, vtb);
  attn_kernel<<<dim3(128, 8), 128, 0, stream>>>(qb, kb, vtb, out);
}